// Round 10
// baseline (545.775 us; speedup 1.0000x reference)
//
#include <hip/hip_runtime.h>
#include <math.h>

#define NBINS 100
#define TDIM  101          // joint table 101x101; index 100 = "out-of-range" row/col
#define SH_W  5120         // ceil(101*101/2) = 5101 u32 words, padded (stray masked reads safe)
static constexpr float LM1f  = -4.605170185988091f;  // log(0.01)
static constexpr float LM2f  =  5.991464547107982f;  // log(400)
static constexpr float EPSV  = 1e-5f;
static constexpr float BETA  = 0.1f;

// Workspace (uint32 units): [0]=sumsq(float), [1..100]=hist_pred, [101..200]=hist_act
//
// HW model (R2-R9): LDS atomic pipe = ~1 lane-op/cy/CU regardless of banking ->
// 109 us floor at 1 atomic/value. VALU-offload unforceable (R7/R8/R9 all spilled).
// This round: JOINT 101x101 u16 2D histogram -- each (pred,act) PAIR = ONE atomic
// (0.5 atomics/value -> ~55 us DS wall). bp'=100 / ba'=100 encode out-of-range;
// pred marginal = row sums (incl null col), act marginal = col sums (incl null row),
// null-null bin drops out. Max count/bin/block = 20480 < 65535: u16 halves safe for
// ANY data. Epilogue: coherent 51-lane row reads + parity-tracked column accums.
__global__ __launch_bounds__(256, 4) void mse_hist_kernel(
    const float4* __restrict__ pred4, const float4* __restrict__ act4,
    const float* __restrict__ pred_s, const float* __restrict__ act_s,
    long long n,
    float* __restrict__ sumsq, unsigned int* __restrict__ hp,
    unsigned int* __restrict__ ha)
{
    __shared__ unsigned int sh[SH_W];          // 20.5 KB joint table (u16 halves)
    __shared__ unsigned int colbuf[TDIM + 1];  // act-marginal combine buffer
    __shared__ float wsum[4];
    const int tid = threadIdx.x;
    for (int i = tid; i < SH_W; i += 256) sh[i] = 0u;
    if (tid < TDIM + 1) colbuf[tid] = 0u;
    __syncthreads();

    const float scale = (float)NBINS / (LM2f - LM1f);

#define JBIN(xv, B) do {                                              \
        float x_ = (xv);                                              \
        int  b_ = (int)((x_ - LM1f) * scale);                         \
        b_ = b_ < 0 ? 0 : (b_ > NBINS - 1 ? NBINS - 1 : b_);          \
        B = (x_ >= LM1f && x_ <= LM2f) ? b_ : NBINS;                  \
    } while (0)

    // One pair -> one LDS atomic. half-index h in [0, 10200]; inc = 1 or 1<<16.
#define JPAIR(pv, av) do {                                            \
        int bp_, ba_;                                                 \
        JBIN(pv, bp_); JBIN(av, ba_);                                 \
        int h_ = bp_ * TDIM + ba_;                                    \
        atomicAdd(&sh[h_ >> 1], 1u << ((h_ & 1) << 4));               \
    } while (0)

    float acc = 0.f;
    const long long n8     = n >> 3;
    const long long stride = (long long)gridDim.x * 256;
    long long i = (long long)blockIdx.x * 256 + tid;

    // 2-deep register pipeline (R5-proven): next tile's loads issued before consume.
    float4 p0, p1, a0, a1;
    bool have = (i < n8);
    if (have) {
        p0 = pred4[2 * i]; p1 = pred4[2 * i + 1];
        a0 = act4[2 * i];  a1 = act4[2 * i + 1];
    }
    while (have) {
        const long long ni = i + stride;
        const bool hn = (ni < n8);
        float4 q0, q1, b0, b1;
        if (hn) {
            q0 = pred4[2 * ni]; q1 = pred4[2 * ni + 1];
            b0 = act4[2 * ni];  b1 = act4[2 * ni + 1];
        }
        float d;
        d = p0.x - a0.x; acc = fmaf(d, d, acc);
        d = p0.y - a0.y; acc = fmaf(d, d, acc);
        d = p0.z - a0.z; acc = fmaf(d, d, acc);
        d = p0.w - a0.w; acc = fmaf(d, d, acc);
        d = p1.x - a1.x; acc = fmaf(d, d, acc);
        d = p1.y - a1.y; acc = fmaf(d, d, acc);
        d = p1.z - a1.z; acc = fmaf(d, d, acc);
        d = p1.w - a1.w; acc = fmaf(d, d, acc);

        JPAIR(p0.x, a0.x); JPAIR(p0.y, a0.y);
        JPAIR(p0.z, a0.z); JPAIR(p0.w, a0.w);
        JPAIR(p1.x, a1.x); JPAIR(p1.y, a1.y);
        JPAIR(p1.z, a1.z); JPAIR(p1.w, a1.w);

        p0 = q0; p1 = q1; a0 = b0; a1 = b1;
        i = ni; have = hn;
    }

    // Scalar tail (n % 8 != 0) — thread 0 of block 0, same joint path.
    if (blockIdx.x == 0 && tid == 0) {
        for (long long j = 8 * n8; j < n; ++j) {
            float p = pred_s[j], a = act_s[j];
            float d = p - a; acc = fmaf(d, d, acc);
            JPAIR(p, a);
        }
    }
#undef JPAIR
    __syncthreads();

    // ---- Marginalization ----
    // Row bp occupies half-indices 101*bp .. 101*bp+100 (51 words, lanes 0..50).
    // Even bp: lane k word holds cols (2k lo, 2k+1 hi); lane 50 hi = next row -> mask.
    // Odd  bp: lane k word holds cols (2k-1 lo, 2k hi); lane 0 lo = prev row -> mask.
    // Row sum (cols 0..100) -> hp[bp] (skip null row 100).
    // Column accumulators (parity-tracked) -> act marginal over ALL rows incl row 100.
    const int wv = tid >> 6, k = tid & 63;
    unsigned int aEL = 0, aEH = 0, aOL = 0, aOH = 0;
    for (int bp = wv; bp <= NBINS; bp += 4) {
        const int wst = (bp * TDIM) >> 1;
        unsigned int v = (k <= 50) ? sh[wst + k] : 0u;
        unsigned int lo = v & 0xFFFFu, hi = v >> 16;
        if (bp & 1) { if (k == 0)  lo = 0u; }
        else        { if (k == 50) hi = 0u; }
        unsigned int rs = lo + hi;
        for (int off = 32; off > 0; off >>= 1) rs += __shfl_down(rs, off);
        if (k == 0 && bp < NBINS && rs) atomicAdd(&hp[bp], rs);
        if (bp & 1) { aOL += lo; aOH += hi; }
        else        { aEL += lo; aEH += hi; }
    }
    // col[2k] = aEL[k] + aOH[k];  col[2k+1] = aEH[k] + aOL[k+1]
    unsigned int aOLn = __shfl_down(aOL, 1);
    if (k <= 49) {
        unsigned int cA = aEL + aOH;
        unsigned int cB = aEH + aOLn;
        if (cA) atomicAdd(&colbuf[2 * k], cA);
        if (cB) atomicAdd(&colbuf[2 * k + 1], cB);
    }
    __syncthreads();
    if (tid < NBINS) {
        unsigned int cv = colbuf[tid];
        if (cv) atomicAdd(&ha[tid], cv);
    }
#undef JBIN

    // Block-reduce squared-diff (wave64 shuffle, then LDS).
    for (int off = 32; off > 0; off >>= 1)
        acc += __shfl_down(acc, off);
    if ((tid & 63) == 0) wsum[wv] = acc;
    __syncthreads();
    if (tid == 0)
        atomicAdd(sumsq, wsum[0] + wsum[1] + wsum[2] + wsum[3]);
}

// Kernel 2: normalize histograms, KLD, combine with MSE. One block, 128 threads.
__global__ __launch_bounds__(128) void finalize_kernel(
    const float* __restrict__ sumsq, const unsigned int* __restrict__ hp,
    const unsigned int* __restrict__ ha, float* __restrict__ out, float n_elems)
{
    const int t = threadIdx.x;
    float hpv = 0.f, hav = 0.f;
    if (t < NBINS) {
        hpv = (float)hp[t] + EPSV;
        hav = (float)ha[t] + EPSV;
    }
    float sp = hpv, sa = hav;
    for (int off = 32; off > 0; off >>= 1) {
        sp += __shfl_down(sp, off);
        sa += __shfl_down(sa, off);
    }
    __shared__ float shp[2], sha[2];
    if ((t & 63) == 0) { shp[t >> 6] = sp; sha[t >> 6] = sa; }
    __syncthreads();
    const float tot_p = shp[0] + shp[1];
    const float tot_a = sha[0] + sha[1];

    float term = 0.f;
    if (t < NBINS) {
        float pv = hpv / tot_p;
        float av = hav / tot_a;
        term = av * (logf(av) - logf(pv));
    }
    for (int off = 32; off > 0; off >>= 1)
        term += __shfl_down(term, off);
    __shared__ float st[2];
    if ((t & 63) == 0) st[t >> 6] = term;
    __syncthreads();
    if (t == 0) {
        float kld = (st[0] + st[1]) / (float)NBINS;
        out[0] = sumsq[0] / n_elems + BETA * kld;
    }
}

extern "C" void kernel_launch(void* const* d_in, const int* in_sizes, int n_in,
                              void* d_out, int out_size, void* d_ws, size_t ws_size,
                              hipStream_t stream) {
    const float* pred = (const float*)d_in[0];
    const float* act  = (const float*)d_in[1];
    const long long n = (long long)in_sizes[0];

    float*        sumsq = (float*)d_ws;
    unsigned int* hp    = (unsigned int*)d_ws + 1;
    unsigned int* ha    = (unsigned int*)d_ws + 1 + NBINS;

    hipMemsetAsync(d_ws, 0, (1 + 2 * NBINS) * sizeof(unsigned int), stream);

    // 1792 blocks = 7 blocks/CU (20.9 KB LDS each, 146 KB/CU) -> 28 waves/CU.
    // Values/block <= 20480 < 65535 -> u16 joint counters overflow-proof.
    mse_hist_kernel<<<1792, 256, 0, stream>>>(
        (const float4*)pred, (const float4*)act, pred, act, n, sumsq, hp, ha);

    finalize_kernel<<<1, 128, 0, stream>>>(sumsq, hp, ha, (float*)d_out, (float)n);
}